// Round 7
// baseline (619.037 us; speedup 1.0000x reference)
//
#include <hip/hip_runtime.h>
#include <stdint.h>

typedef unsigned short u16;
typedef __attribute__((ext_vector_type(8))) short s8v;    // 8 x bf16
typedef __attribute__((ext_vector_type(4))) float f4v;    // 4 x f32
typedef __fp16 h2v __attribute__((ext_vector_type(2)));   // 2 x f16

__device__ __forceinline__ float bu2f(u16 u) {
  return __uint_as_float(((uint32_t)u) << 16);
}
__device__ __forceinline__ u16 f2bu(float f) {
  uint32_t u = __float_as_uint(f);
  u += 0x7fffu + ((u >> 16) & 1u);  // RNE
  return (u16)(u >> 16);
}
__device__ __forceinline__ u16 f2h16(float f) {
  __fp16 h = (__fp16)f;
  u16 r;
  __builtin_memcpy(&r, &h, 2);
  return r;
}
// runtime-dtype input load (mode: 0 = bf16, 1 = f32); branch is wave-uniform
__device__ __forceinline__ float ldin(int m, const void* p, long i) {
  return m ? ((const float*)p)[i] : bu2f(((const u16*)p)[i]);
}

union U32H2 { uint32_t u; h2v h; };

__device__ __forceinline__ uint32_t pk2h(float a, float b) {
  U32H2 x;
  x.h = __builtin_amdgcn_cvt_pkrtz(a, b);  // exact for bf16-valued inputs
  return x.u;
}

#if __has_builtin(__builtin_amdgcn_fdot2)
__device__ __forceinline__ float fdot2u(uint32_t a, uint32_t b, float c) {
  U32H2 ua, ub;
  ua.u = a; ub.u = b;
  return __builtin_amdgcn_fdot2(ua.h, ub.h, c, false);
}
#else
__device__ __forceinline__ float fdot2u(uint32_t a, uint32_t b, float c) {
  U32H2 ua, ub;
  ua.u = a; ub.u = b;
  c = fmaf((float)ua.h.x, (float)ub.h.x, c);
  return fmaf((float)ua.h.y, (float)ub.h.y, c);
}
#endif

// ---------------------------------------------------------------------------
// k_init: dtype detect + conv-weight f16-pair packing, one block.
// ---------------------------------------------------------------------------
__global__ __launch_bounds__(256) void k_init(
    const u16* __restrict__ x,
    const void* __restrict__ c1w, const void* __restrict__ c1b,
    const void* __restrict__ c2w, const void* __restrict__ c2b,
    int* __restrict__ flag, uint32_t* __restrict__ cdw) {
  __shared__ int s[256];
  __shared__ int smode;
  const int tid = threadIdx.x;
  int cnt = 0;
  for (int i = tid; i < 2048; i += 256) {
    int e = (x[i] >> 7) & 0xFF;
    cnt += (e >= 96 && e <= 134) ? 1 : 0;
  }
  s[tid] = cnt;
  __syncthreads();
  if (tid == 0) {
    int t = 0;
    for (int i = 0; i < 256; ++i) t += s[i];
    int m = (t >= 1843) ? 0 : 1;  // 0 = bf16, 1 = f32
    *flag = m;
    smode = m;
  }
  __syncthreads();
  const int mode = smode;
  for (int i = tid; i < 1732; i += 256) {
    if (i < 270) {            // cd1: [6c][3ic][5ky][3p]
      int p = i % 3, ky = (i / 3) % 5, ic = (i / 15) % 3, c = i / 45;
      long b = (((long)c * 3 + ic) * 5 + ky) * 5;
      float w0 = ldin(mode, c1w, b + 2 * p);
      float w1 = (2 * p + 1 < 5) ? ldin(mode, c1w, b + 2 * p + 1) : 0.f;
      cdw[i] = (uint32_t)f2h16(w0) | ((uint32_t)f2h16(w1) << 16);
    } else if (i < 1710) {    // cd2: [16c][6ic][5ky][3p]
      int j = i - 270;
      int p = j % 3, ky = (j / 3) % 5, ic = (j / 15) % 6, c = j / 90;
      long b = (((long)c * 6 + ic) * 5 + ky) * 5;
      float w0 = ldin(mode, c2w, b + 2 * p);
      float w1 = (2 * p + 1 < 5) ? ldin(mode, c2w, b + 2 * p + 1) : 0.f;
      cdw[i] = (uint32_t)f2h16(w0) | ((uint32_t)f2h16(w1) << 16);
    } else if (i < 1716) {    // cb1 (f32)
      ((float*)(cdw + 1710))[i - 1710] = ldin(mode, c1b, i - 1710);
    } else {                  // cb2 (f32)
      ((float*)(cdw + 1716))[i - 1716] = ldin(mode, c2b, i - 1716);
    }
  }
}

// ---------------------------------------------------------------------------
// Conv kernel v4: f16 LDS + v_dot2_f32_f16; sxh row stride 38 u16 (odd dword
// stride -> all 32 banks); __launch_bounds__(256,3) for register headroom.
// Also folds the big MFMA weight-transpose (852k items) into its tail.
// Out p2: [B][416] bf16, cols 400..415 zero.
// ---------------------------------------------------------------------------
#define CIMG 5
#define SXW 38
__global__ __launch_bounds__(256, 3) void k_conv(
    const int* __restrict__ flag,
    const void* __restrict__ x,
    const uint32_t* __restrict__ cdw,
    const void* __restrict__ fc1w, const void* __restrict__ fc2w,
    const void* __restrict__ ew1, const void* __restrict__ ew2,
    u16* __restrict__ p2,
    u16* __restrict__ fc1t, u16* __restrict__ fc2t,
    u16* __restrict__ w1t, u16* __restrict__ w2t,
    int Btot) {
  __shared__ u16 sxh[CIMG * 3 * 32 * SXW];  // f16, 36,480 B
  __shared__ u16 sp1h[CIMG * 6 * 14 * 18];  // f16, 15,120 B
  const int mode = *flag;
  const uint32_t* cd1 = cdw;
  const uint32_t* cd2 = cdw + 270;
  const float* cb1 = (const float*)(cdw + 1710);
  const float* cb2 = (const float*)(cdw + 1716);
  const int tid = threadIdx.x;
  const long gimg0 = (long)blockIdx.x * CIMG;

  // zero pad columns (sxh cols 32..37, sp1h cols 14..17)
  for (int r = tid; r < CIMG * 96; r += 256) {
    *(uint32_t*)(sxh + (size_t)r * SXW + 32) = 0;
    *(uint32_t*)(sxh + (size_t)r * SXW + 34) = 0;
    *(uint32_t*)(sxh + (size_t)r * SXW + 36) = 0;
  }
  for (int r = tid; r < CIMG * 84; r += 256) {
    *(uint32_t*)(sp1h + (size_t)r * 18 + 14) = 0;
    *(uint32_t*)(sp1h + (size_t)r * 18 + 16) = 0;
  }

  // stage x -> f16 LDS
  for (int i = tid; i < CIMG * 96; i += 256) {
    int img = i / 96, rem = i - img * 96;
    if (gimg0 + img < Btot) {
      long goff = (gimg0 + img) * 3072 + (long)rem * 32;
      u16* dst = sxh + (size_t)i * SXW;
      if (!mode) {
        const uint32_t* src = (const uint32_t*)((const u16*)x + goff);
#pragma unroll
        for (int j = 0; j < 16; ++j) {
          uint32_t d = src[j];
          *(uint32_t*)(dst + 2 * j) =
              pk2h(__uint_as_float(d << 16), __uint_as_float(d & 0xffff0000u));
        }
      } else {
        const float* src = (const float*)x + goff;
#pragma unroll
        for (int j = 0; j < 16; ++j)
          *(uint32_t*)(dst + 2 * j) = pk2h(src[2 * j], src[2 * j + 1]);
      }
    }
  }
  __syncthreads();

  // conv1 + relu + pool: task = (img, pooled pos), all 6 channels
  for (int task = tid; task < CIMG * 196; task += 256) {
    int img = task / 196, pos = task - img * 196;
    if (gimg0 + img >= Btot) continue;
    int py = pos / 14, px = pos - py * 14;
    int x0 = 2 * px, y0 = 2 * py;
    float acc[6][4];
#pragma unroll
    for (int c = 0; c < 6; ++c) {
      float bv = cb1[c];
      acc[c][0] = bv; acc[c][1] = bv; acc[c][2] = bv; acc[c][3] = bv;
    }
    for (int ic = 0; ic < 3; ++ic) {
      uint32_t A[6][4], S[6][3];
      const u16* rb = sxh + ((size_t)(img * 3 + ic) * 32 + y0) * SXW + x0;
#pragma unroll
      for (int r = 0; r < 6; ++r) {
#pragma unroll
        for (int p = 0; p < 4; ++p)
          A[r][p] = *(const uint32_t*)(rb + (size_t)r * SXW + 2 * p);
#pragma unroll
        for (int p = 0; p < 3; ++p)
          S[r][p] = (A[r][p] >> 16) | (A[r][p + 1] << 16);
      }
#pragma unroll
      for (int c = 0; c < 6; ++c) {
        const uint32_t* wb = cd1 + ((c * 3 + ic) * 5) * 3;
#pragma unroll
        for (int ky = 0; ky < 5; ++ky) {
#pragma unroll
          for (int p = 0; p < 3; ++p) {
            uint32_t w = wb[ky * 3 + p];
            acc[c][0] = fdot2u(A[ky][p], w, acc[c][0]);
            acc[c][1] = fdot2u(S[ky][p], w, acc[c][1]);
            acc[c][2] = fdot2u(A[ky + 1][p], w, acc[c][2]);
            acc[c][3] = fdot2u(S[ky + 1][p], w, acc[c][3]);
          }
        }
      }
    }
#pragma unroll
    for (int c = 0; c < 6; ++c) {
      float m = fmaxf(0.f, fmaxf(fmaxf(acc[c][0], acc[c][1]),
                                 fmaxf(acc[c][2], acc[c][3])));
      sp1h[((size_t)(img * 6 + c) * 14 + py) * 18 + px] = f2h16(m);
    }
  }
  __syncthreads();

  // conv2 + relu + pool: task = (img, 4-channel group, pooled pos)
  for (int task = tid; task < CIMG * 100; task += 256) {
    int img = task / 100, r0 = task - img * 100;
    if (gimg0 + img >= Btot) continue;
    int grp = r0 / 25, pos = r0 - grp * 25;
    int py = pos / 5, px = pos - py * 5;
    int x0 = 2 * px, y0 = 2 * py;
    int c0 = grp * 4;
    float acc[4][4];
#pragma unroll
    for (int c = 0; c < 4; ++c) {
      float bv = cb2[c0 + c];
      acc[c][0] = bv; acc[c][1] = bv; acc[c][2] = bv; acc[c][3] = bv;
    }
    for (int ic = 0; ic < 6; ++ic) {
      uint32_t A[6][4], S[6][3];
      const u16* rb = sp1h + ((size_t)(img * 6 + ic) * 14 + y0) * 18 + x0;
#pragma unroll
      for (int r = 0; r < 6; ++r) {
#pragma unroll
        for (int p = 0; p < 4; ++p)
          A[r][p] = *(const uint32_t*)(rb + (size_t)r * 18 + 2 * p);
#pragma unroll
        for (int p = 0; p < 3; ++p)
          S[r][p] = (A[r][p] >> 16) | (A[r][p + 1] << 16);
      }
#pragma unroll
      for (int c = 0; c < 4; ++c) {
        const uint32_t* wb = cd2 + (((c0 + c) * 6 + ic) * 5) * 3;
#pragma unroll
        for (int ky = 0; ky < 5; ++ky) {
#pragma unroll
          for (int p = 0; p < 3; ++p) {
            uint32_t w = wb[ky * 3 + p];
            acc[c][0] = fdot2u(A[ky][p], w, acc[c][0]);
            acc[c][1] = fdot2u(S[ky][p], w, acc[c][1]);
            acc[c][2] = fdot2u(A[ky + 1][p], w, acc[c][2]);
            acc[c][3] = fdot2u(S[ky + 1][p], w, acc[c][3]);
          }
        }
      }
    }
    u16* pout = p2 + (gimg0 + img) * 416;
#pragma unroll
    for (int c = 0; c < 4; ++c) {
      float m = fmaxf(0.f, fmaxf(fmaxf(acc[c][0], acc[c][1]),
                                 fmaxf(acc[c][2], acc[c][3])));
      pout[(c0 + c) * 25 + py * 5 + px] = f2bu(m);
    }
  }

  // zero K-pad cols 400..415
  for (int i = tid; i < CIMG * 16; i += 256) {
    int img = i / 16;
    if (gimg0 + img < Btot) p2[(gimg0 + img) * 416 + 400 + (i & 15)] = 0;
  }

  // ---- folded big weight-transpose: 851,968 items over the grid ----
  // (consumers k_fcA / k_exp run strictly after this kernel in stream order)
  {
    long base = (long)blockIdx.x * 260;
    long end = base + 260;
    if (end > 851968) end = 851968;
    for (long gid = base + tid; gid < end; gid += 256) {
      if (gid < 53248) {                   // fc1t: [128 n][416 k]
        int n = (int)(gid / 416), k = (int)(gid % 416);
        fc1t[gid] = (n < 120 && k < 400)
                        ? f2bu(ldin(mode, fc1w, (long)k * 120 + n)) : (u16)0;
      } else if (gid < 65536) {            // fc2t: [96 n][128 k]
        long i = gid - 53248;
        int n = (int)(i / 128), k = (int)(i % 128);
        fc2t[i] = (n < 84 && k < 120)
                      ? f2bu(ldin(mode, fc2w, (long)k * 84 + n)) : (u16)0;
      } else if (gid < 458752) {           // w1t: [2][2048 n][96 k]
        long i = gid - 65536;
        int e = (int)(i / 196608);
        long r = i % 196608;
        int n = (int)(r / 96), k = (int)(r % 96);
        w1t[i] = (k < 84)
                     ? f2bu(ldin(mode, ew1, ((long)e * 84 + k) * 2048 + n)) : (u16)0;
      } else {                             // w2t: [2][96 n][2048 k]
        long i = gid - 458752;
        int e = (int)(i / 196608);
        long r = i % 196608;
        int n = (int)(r / 2048), k = (int)(r % 2048);
        w2t[i] = (n < 84)
                     ? f2bu(ldin(mode, ew2, ((long)e * 2048 + k) * 84 + n)) : (u16)0;
      }
    }
  }
}

// ---------------------------------------------------------------------------
// fcA: fc1 -> fc2 -> gate. 64 tokens/block; writes a2buf [B][104] bf16 +
// scbuf [B][2] f32. MFMA layouts as proven in R3.
// ---------------------------------------------------------------------------
__global__ __launch_bounds__(256, 2) void k_fcA(
    const int* __restrict__ flag,
    const u16* __restrict__ p2,
    const u16* __restrict__ fc1t, const u16* __restrict__ fc2t,
    const void* __restrict__ fc1b, const void* __restrict__ fc2b,
    const void* __restrict__ gw,
    u16* __restrict__ a2buf, float* __restrict__ scbuf) {
  __shared__ __align__(16) char smem[62976];
  u16* a2s = (u16*)smem;                    // [64][104]
  u16* hs = (u16*)(smem + 13312);           // [64][136]
  u16* wbuf = (u16*)(smem + 31232);
  u16* xs = (u16*)(smem + 57856);           // [64][40]

  const int mode = *flag;
  const int tid = threadIdx.x;
  const int wv = tid >> 6, ln = tid & 63;
  const int m = ln & 15, quad = ln >> 4;
  const long t0 = (long)blockIdx.x * 64;
  const int row0 = wv * 16 + quad * 4;

  for (int i = tid; i < 30720 / 4; i += 256) ((uint32_t*)smem)[i] = 0;

  // fc1
  f4v acc1[8];
#pragma unroll
  for (int i = 0; i < 8; ++i) acc1[i] = (f4v){0.f, 0.f, 0.f, 0.f};
  for (int s = 0; s < 13; ++s) {
    {
      int r = tid >> 2, c0 = (tid & 3) * 8;
      *(uint4*)(xs + r * 40 + c0) =
          *(const uint4*)(p2 + (t0 + r) * 416 + s * 32 + c0);
      int n = tid >> 1, cw = (tid & 1) * 16;
      *(uint4*)(wbuf + n * 40 + cw) = *(const uint4*)(fc1t + (long)n * 416 + s * 32 + cw);
      *(uint4*)(wbuf + n * 40 + cw + 8) =
          *(const uint4*)(fc1t + (long)n * 416 + s * 32 + cw + 8);
    }
    __syncthreads();
    s8v a = *(const s8v*)(xs + (wv * 16 + m) * 40 + quad * 8);
#pragma unroll
    for (int nt = 0; nt < 8; ++nt) {
      s8v b = *(const s8v*)(wbuf + (nt * 16 + m) * 40 + quad * 8);
      acc1[nt] = __builtin_amdgcn_mfma_f32_16x16x32_bf16(a, b, acc1[nt], 0, 0, 0);
    }
    __syncthreads();
  }
#pragma unroll
  for (int nt = 0; nt < 8; ++nt) {
    int n = nt * 16 + m;
    if (n < 120) {
      float bv = ldin(mode, fc1b, n);
#pragma unroll
      for (int r = 0; r < 4; ++r)
        hs[(row0 + r) * 136 + n] = f2bu(fmaxf(acc1[nt][r] + bv, 0.f));
    }
  }
  __syncthreads();

  // fc2
  for (int i = tid; i < 1536; i += 256) {
    int n = i >> 4, c0 = (i & 15) * 8;
    *(uint4*)(wbuf + n * 136 + c0) = *(const uint4*)(fc2t + n * 128 + c0);
  }
  __syncthreads();
  f4v acc2[6];
#pragma unroll
  for (int i = 0; i < 6; ++i) acc2[i] = (f4v){0.f, 0.f, 0.f, 0.f};
  for (int s = 0; s < 4; ++s) {
    s8v a = *(const s8v*)(hs + (wv * 16 + m) * 136 + s * 32 + quad * 8);
#pragma unroll
    for (int nt = 0; nt < 6; ++nt) {
      s8v b = *(const s8v*)(wbuf + (nt * 16 + m) * 136 + s * 32 + quad * 8);
      acc2[nt] = __builtin_amdgcn_mfma_f32_16x16x32_bf16(a, b, acc2[nt], 0, 0, 0);
    }
  }
  __syncthreads();
#pragma unroll
  for (int nt = 0; nt < 6; ++nt) {
    int n = nt * 16 + m;
    if (n < 84) {
      float bv = ldin(mode, fc2b, n);
#pragma unroll
      for (int r = 0; r < 4; ++r)
        a2s[(row0 + r) * 104 + n] = f2bu(fmaxf(acc2[nt][r] + bv, 0.f));
    }
  }
  __syncthreads();

  // gate + writeback
  if (tid < 64) {
    const u16* xr = a2s + tid * 104;
    float l0 = 0.f, l1 = 0.f;
    for (int k = 0; k < 84; ++k) {
      float xv = bu2f(xr[k]);
      l0 = fmaf(xv, ldin(mode, gw, 2 * k), l0);
      l1 = fmaf(xv, ldin(mode, gw, 2 * k + 1), l1);
    }
    float mx = fmaxf(l0, l1);
    float e0 = __expf(l0 - mx), e1 = __expf(l1 - mx);
    float inv = 1.f / (e0 + e1);
    *(float2*)(scbuf + (t0 + tid) * 2) = make_float2(e0 * inv, e1 * inv);
  }
  for (int i = tid; i < 832; i += 256) {  // 64 rows x 13 uint4
    int r = i / 13, c0 = (i - r * 13) * 8;
    *(uint4*)(a2buf + (t0 + r) * 104 + c0) = *(const uint4*)(a2s + r * 104 + c0);
  }
}

// ---------------------------------------------------------------------------
// exp: one expert per block (grid = [B/64, 2]) -> ybuf [2][B][96] f32.
// ---------------------------------------------------------------------------
__global__ __launch_bounds__(256, 2) void k_exp(
    const int* __restrict__ flag,
    const u16* __restrict__ a2buf, const float* __restrict__ scbuf,
    const u16* __restrict__ w1t, const u16* __restrict__ w2t,
    const void* __restrict__ eb1, const void* __restrict__ eb2,
    float* __restrict__ ybuf, int Btok) {
  __shared__ __align__(16) char smem[57856];
  u16* a2s = (u16*)smem;                    // [64][104]
  u16* hs = (u16*)(smem + 13312);           // [64][136]
  u16* wbuf = (u16*)(smem + 30720);         // 26,624 B
  float* scs = (float*)(smem + 57344);      // [64]

  const int mode = *flag;
  const int tid = threadIdx.x;
  const int wv = tid >> 6, ln = tid & 63;
  const int m = ln & 15, quad = ln >> 4;
  const int e = blockIdx.y;
  const long t0 = (long)blockIdx.x * 64;
  const int row0 = wv * 16 + quad * 4;
  const u16* w1te = w1t + (long)e * 196608;
  const u16* w2te = w2t + (long)e * 196608;

  for (int i = tid; i < 832; i += 256) {
    int r = i / 13, c0 = (i - r * 13) * 8;
    *(uint4*)(a2s + r * 104 + c0) = *(const uint4*)(a2buf + (t0 + r) * 104 + c0);
  }
  if (tid < 64) scs[tid] = scbuf[(t0 + tid) * 2 + e];
  __syncthreads();

  f4v acce[6];
#pragma unroll
  for (int i = 0; i < 6; ++i) acce[i] = (f4v){0.f, 0.f, 0.f, 0.f};
  for (int c = 0; c < 16; ++c) {
    const int n0 = c * 128;
    if (c) __syncthreads();
    for (int i = tid; i < 1536; i += 256) {  // wbuf[128][104] <- w1t chunk
      int nl = i / 12, c0 = (i - nl * 12) * 8;
      *(uint4*)(wbuf + nl * 104 + c0) =
          *(const uint4*)(w1te + (long)(n0 + nl) * 96 + c0);
    }
    __syncthreads();
    f4v acch[8];
#pragma unroll
    for (int i = 0; i < 8; ++i) acch[i] = (f4v){0.f, 0.f, 0.f, 0.f};
    for (int s = 0; s < 3; ++s) {
      s8v a = *(const s8v*)(a2s + (wv * 16 + m) * 104 + s * 32 + quad * 8);
#pragma unroll
      for (int nt = 0; nt < 8; ++nt) {
        s8v b = *(const s8v*)(wbuf + (nt * 16 + m) * 104 + s * 32 + quad * 8);
        acch[nt] = __builtin_amdgcn_mfma_f32_16x16x32_bf16(a, b, acch[nt], 0, 0, 0);
      }
    }
#pragma unroll
    for (int nt = 0; nt < 8; ++nt) {
      float bv = ldin(mode, eb1, (long)e * 2048 + n0 + nt * 16 + m);
#pragma unroll
      for (int r = 0; r < 4; ++r)
        hs[(row0 + r) * 136 + nt * 16 + m] = f2bu(fmaxf(acch[nt][r] + bv, 0.f));
    }
    __syncthreads();
    for (int i = tid; i < 1536; i += 256) {  // wbuf[96][136] <- w2t slice
      int n = i >> 4, c0 = (i & 15) * 8;
      *(uint4*)(wbuf + n * 136 + c0) =
          *(const uint4*)(w2te + (long)n * 2048 + n0 + c0);
    }
    __syncthreads();
    for (int s = 0; s < 4; ++s) {
      s8v a = *(const s8v*)(hs + (wv * 16 + m) * 136 + s * 32 + quad * 8);
#pragma unroll
      for (int nt = 0; nt < 6; ++nt) {
        s8v b = *(const s8v*)(wbuf + (nt * 16 + m) * 136 + s * 32 + quad * 8);
        acce[nt] = __builtin_amdgcn_mfma_f32_16x16x32_bf16(a, b, acce[nt], 0, 0, 0);
      }
    }
  }

  // y_e = sc * (acce + b2) -> ybuf
#pragma unroll
  for (int nt = 0; nt < 6; ++nt) {
    int d = nt * 16 + m;
    float bv = (d < 84) ? ldin(mode, eb2, (long)e * 84 + d) : 0.f;
#pragma unroll
    for (int r = 0; r < 4; ++r) {
      float sc = scs[row0 + r];
      ybuf[((size_t)e * Btok + t0 + row0 + r) * 96 + d] = sc * (acce[nt][r] + bv);
    }
  }
}

// ---------------------------------------------------------------------------
// fc3: out = (y0 + y1) @ w3 + b3. 64 tokens/block.
// ---------------------------------------------------------------------------
__global__ __launch_bounds__(256) void k_fc3(
    const int* __restrict__ flag,
    const float* __restrict__ ybuf,
    const void* __restrict__ w3, const void* __restrict__ b3,
    void* __restrict__ out, int Btok) {
  __shared__ float sw3[840];
  __shared__ float sb3[10];
  const int mode = *flag;
  const int tid = threadIdx.x;
  const long t0 = (long)blockIdx.x * 64;
  for (int i = tid; i < 840; i += 256) sw3[i] = ldin(mode, w3, i);
  if (tid < 10) sb3[tid] = ldin(mode, b3, tid);
  __syncthreads();
  for (int idx = tid; idx < 640; idx += 256) {
    int tk = idx / 10, cc = idx - tk * 10;
    const float* y0r = ybuf + (t0 + tk) * 96;
    const float* y1r = ybuf + ((size_t)Btok + t0 + tk) * 96;
    float acc = sb3[cc];
    for (int d = 0; d < 84; ++d)
      acc = fmaf(y0r[d] + y1r[d], sw3[d * 10 + cc], acc);
    long oi = (t0 + tk) * 10 + cc;
    if (mode) ((float*)out)[oi] = acc;
    else ((u16*)out)[oi] = f2bu(acc);
  }
}

// ---------------------------------------------------------------------------
extern "C" void kernel_launch(void* const* d_in, const int* in_sizes, int n_in,
                              void* d_out, int out_size, void* d_ws, size_t ws_size,
                              hipStream_t stream) {
  const int B = in_sizes[0] / 3072;  // 16384
  char* wsb = (char*)d_ws;
  int* flag = (int*)wsb;
  u16* p2 = (u16*)(wsb + 64);                    // [B][416] bf16
  u16* fc1t = p2 + (size_t)B * 416;              // 53,248 elems
  u16* fc2t = fc1t + 53248;                      // 12,288
  u16* w1t = fc2t + 12288;                       // 393,216
  u16* w2t = w1t + 393216;                       // 393,216
  uint32_t* cdw = (uint32_t*)(w2t + 393216);     // 1,732 dwords
  u16* a2buf = (u16*)(cdw + 1732);               // [B][104] bf16
  float* scbuf = (float*)(a2buf + (size_t)B * 104);  // [B][2] f32
  float* ybuf = scbuf + (size_t)B * 2;           // [2][B][96] f32

  k_init<<<1, 256, 0, stream>>>((const u16*)d_in[0], d_in[1], d_in[2],
                                d_in[3], d_in[4], flag, cdw);

  const int convGrid = (B + CIMG - 1) / CIMG;
  k_conv<<<convGrid, 256, 0, stream>>>(flag, d_in[0], cdw, d_in[5], d_in[7],
                                       d_in[10], d_in[12], p2, fc1t, fc2t,
                                       w1t, w2t, B);

  k_fcA<<<B / 64, 256, 0, stream>>>(flag, p2, fc1t, fc2t, d_in[6], d_in[8],
                                    d_in[9], a2buf, scbuf);

  dim3 eg(B / 64, 2);
  k_exp<<<eg, 256, 0, stream>>>(flag, a2buf, scbuf, w1t, w2t, d_in[11],
                                d_in[13], ybuf, B);

  k_fc3<<<B / 64, 256, 0, stream>>>(flag, ybuf, d_in[14], d_in[15], d_out, B);
}